// Round 8
// baseline (306.299 us; speedup 1.0000x reference)
//
#include <hip/hip_runtime.h>
#include <hip/hip_fp16.h>

// LFM2 short-conv block. Round 8: 256x256 GEMM with register-level fragment
// pipelining: each window reads NEXT window's fragments while MFMAing the
// previous window's, vmcnt(2) every window. Reads evened to 4/8/8/4 per wave
// per tile (bf0 held in regs, no re-read).

typedef _Float16 f16x8 __attribute__((ext_vector_type(8)));
typedef float    f32x4 __attribute__((ext_vector_type(4)));

#define GLD_LDS16(gsrc, sdst) \
  __builtin_amdgcn_global_load_lds((const __attribute__((address_space(1))) void*)(gsrc), \
                                   (__attribute__((address_space(3))) void*)(sdst), 16, 0, 0)

#define VMCNT2 asm volatile("s_waitcnt vmcnt(2)" ::: "memory")
#define VMCNT0 asm volatile("s_waitcnt vmcnt(0)" ::: "memory")
#define LGKM0  asm volatile("s_waitcnt lgkmcnt(0)" ::: "memory")
#define BAR    __builtin_amdgcn_s_barrier()
#define SCHED0 __builtin_amdgcn_sched_barrier(0)

// ---------------- fp32 -> fp16 convert (8 elems/thread) ----------------
__global__ __launch_bounds__(256) void cvt_f32_f16(const float* __restrict__ in,
                                                   _Float16* __restrict__ out, int n) {
  int i = blockIdx.x * 256 + threadIdx.x;
  int base = i * 8;
  if (base >= n) return;
  const float4* p = reinterpret_cast<const float4*>(in) + i * 2;
  float4 a = p[0], b = p[1];
  f16x8 o;
  o[0] = (_Float16)a.x; o[1] = (_Float16)a.y; o[2] = (_Float16)a.z; o[3] = (_Float16)a.w;
  o[4] = (_Float16)b.x; o[5] = (_Float16)b.y; o[6] = (_Float16)b.z; o[7] = (_Float16)b.w;
  *reinterpret_cast<f16x8*>(out + base) = o;
}

// ---------------- conv + gating: y = Cg * causal_conv3(Bg * x) ----------------
__global__ __launch_bounds__(256) void conv_gate(const _Float16* __restrict__ BCx,
                                                 const float* __restrict__ Wc,   // [2048,1,3]
                                                 _Float16* __restrict__ Y) {
  const int h0 = threadIdx.x * 8;
  const int r0 = blockIdx.x * 8;
  const int s0 = r0 & 4095;

  float w0[8], w1[8], w2[8];
#pragma unroll
  for (int j = 0; j < 8; ++j) {
    w0[j] = Wc[(h0 + j) * 3 + 0];
    w1[j] = Wc[(h0 + j) * 3 + 1];
    w2[j] = Wc[(h0 + j) * 3 + 2];
  }

  float bxm2[8] = {}, bxm1[8] = {};
  if (s0 != 0) {
    const _Float16* pm2 = BCx + (size_t)(r0 - 2) * 6144 + h0;
    const _Float16* pm1 = BCx + (size_t)(r0 - 1) * 6144 + h0;
    f16x8 bg2 = *reinterpret_cast<const f16x8*>(pm2);
    f16x8 xx2 = *reinterpret_cast<const f16x8*>(pm2 + 4096);
    f16x8 bg1 = *reinterpret_cast<const f16x8*>(pm1);
    f16x8 xx1 = *reinterpret_cast<const f16x8*>(pm1 + 4096);
#pragma unroll
    for (int j = 0; j < 8; ++j) {
      bxm2[j] = (float)bg2[j] * (float)xx2[j];
      bxm1[j] = (float)bg1[j] * (float)xx1[j];
    }
  }

  for (int i = 0; i < 8; ++i) {
    const _Float16* pr = BCx + (size_t)(r0 + i) * 6144 + h0;
    f16x8 bg = *reinterpret_cast<const f16x8*>(pr);
    f16x8 cg = *reinterpret_cast<const f16x8*>(pr + 2048);
    f16x8 xx = *reinterpret_cast<const f16x8*>(pr + 4096);
    f16x8 o;
#pragma unroll
    for (int j = 0; j < 8; ++j) {
      float bx   = (float)bg[j] * (float)xx[j];
      float conv = w0[j] * bxm2[j] + w1[j] * bxm1[j] + w2[j] * bx;
      o[j] = (_Float16)((float)cg[j] * conv);
      bxm2[j] = bxm1[j];
      bxm1[j] = bx;
    }
    *reinterpret_cast<f16x8*>(Y + (size_t)(r0 + i) * 2048 + h0) = o;
  }
}

// ---------------- fragment load helpers ----------------
__device__ __forceinline__ void ldA(f16x8 (&af)[4][2], const _Float16* p, int base, int ak0, int ak1) {
#pragma unroll
  for (int i = 0; i < 4; ++i) {
    af[i][0] = *(const f16x8*)(p + base + i * 1024 + ak0);
    af[i][1] = *(const f16x8*)(p + base + i * 1024 + ak1);
  }
}
__device__ __forceinline__ void ldB(f16x8 (&bf)[2][2], const _Float16* p, int base, int ak0, int ak1) {
#pragma unroll
  for (int j = 0; j < 2; ++j) {
    bf[j][0] = *(const f16x8*)(p + base + j * 1024 + ak0);
    bf[j][1] = *(const f16x8*)(p + base + j * 1024 + ak1);
  }
}
// af = the 4 m-frags of half QM; acc row block = QM*4.
template <int QM, int QN>
__device__ __forceinline__ void mfmaQ(f32x4 (&acc)[8][4], const f16x8 (&af)[4][2], const f16x8 (&bf)[2][2]) {
  __builtin_amdgcn_s_setprio(1);
#pragma unroll
  for (int i = 0; i < 4; ++i)
#pragma unroll
    for (int j = 0; j < 2; ++j)
#pragma unroll
      for (int ks = 0; ks < 2; ++ks)
        acc[QM * 4 + i][QN * 2 + j] =
            __builtin_amdgcn_mfma_f32_16x16x32_f16(af[i][ks], bf[j][ks], acc[QM * 4 + i][QN * 2 + j], 0, 0, 0);
  __builtin_amdgcn_s_setprio(0);
}

// 256x256 NT GEMM, BK=64, 8 waves (2x4), 16x16x32 MFMA, 128KB static LDS.
// A LDS [256][64] fp16, phys 16B-chunk ^= (row&7) [T2]; gld_lds linear dest +
// inverse-swizzled per-lane SOURCE (rule 21).
// Window structure (4 windows/tile, 1 barrier each):
//   {LGKM0; SCHED0; reads(frags for W+1); MFMA(frags read in W-1); stage; VMCNT2; BAR}
// Stage slots: W0:A'{0,2} W1:B'{0,1} W2:B'{2,3} W3:A'{1,3}  (2 DMA/window).
// vmcnt(2) every window -> unit staged in W retired end-(W+1), published BAR,
// readable W+2:  a02'->W2, b01'->W3, b23'->W0(t+1), a13'->W1(t+1).
// Read schedule (for next window's MFMA): W0: bf1(t) [b23(t), readable W0 ok];
// W1: afH(t) [a13(t), ok]; W2: afL(t+1) [a02', ok]; W3: bf0(t+1) [b01', ok].
// MFMA schedule: W0: Q00(afL,bf0) W1: Q01(afL,bf1) W2: Q11(afH,bf1) W3: Q10(afH,bf0).
// bf0 used W0 and W3 (held, no re-read); 2 sets rotated by the 2-tile unroll.
// Overwrite audit: every stage targets units whose last reader finished >=5
// windows earlier (a02 region last read W2(t-1) via prefetch, staged W0(t+1)...).
// ARGS: N = C column stride, K = reduction dim, nbn = N/256.
template <typename CT>
__global__ __launch_bounds__(512, 2) void gemm8p(const _Float16* __restrict__ Ag,
                                                 const _Float16* __restrict__ Bg,
                                                 CT* __restrict__ Cg,
                                                 int N, int K, int nbn) {
  __shared__ __align__(16) char smem[131072];
  const int tid = threadIdx.x, lane = tid & 63, w = tid >> 6;
  const int wr = w >> 2, wc = w & 3;

  // T1: XCD-bijective block swizzle (grid % 8 == 0)
  const int nwg = (int)gridDim.x, q8 = nwg >> 3;
  const int swz = ((int)blockIdx.x & 7) * q8 + ((int)blockIdx.x >> 3);
  const int bm = (swz / nbn) << 8, bn = (swz % nbn) << 8;

  _Float16* const A0 = (_Float16*)(smem);
  _Float16* const B0 = (_Float16*)(smem + 32768);
  _Float16* const A1 = (_Float16*)(smem + 65536);
  _Float16* const B1 = (_Float16*)(smem + 98304);

  const int rr = tid >> 3;
  const int sCol = ((tid & 7) ^ (rr & 7)) * 8;                  // inverse-swizzled source chunk
  const _Float16* aSrc = Ag + (size_t)(bm + rr) * K + sCol;
  const _Float16* bSrc = Bg + (size_t)(bn + (rr >> 5) * 64 + (rr & 31)) * K + sCol;

  // read-side swizzle folds to per-lane constants (row&7 == lane&7 for all read rows)
  const int ak0 = ((lane >> 4) ^ (lane & 7)) * 8;
  const int ak1 = (((lane >> 4) + 4) ^ (lane & 7)) * 8;
  const int aRB = (wr * 128 + (lane & 15)) * 64;
  const int bRB = (wc * 32 + (lane & 15)) * 64;

  const int nt = K >> 6;

#define STG_A(NBO, kt, u) GLD_LDS16(aSrc + (size_t)(u) * 64 * K + (kt) * 64, \
                                    smem + (NBO) + (u) * 8192 + tid * 16)
#define STG_B(NBO, kt, u) GLD_LDS16(bSrc + (size_t)(((u) & 1) * 128 + ((u) >> 1) * 32) * K + (kt) * 64, \
                                    smem + (NBO) + 32768 + (u) * 8192 + tid * 16)

  f16x8 afL[4][2], afH[4][2];          // A low/high halves of current tile
  f16x8 bfA[2][2], bfB[2][2], bfC[2][2]; // bf0 even / bf1 shared / bf0 odd
  f32x4 acc[8][4] = {};

  // prologue: stage tile 0 -> buffer 0, drain, then pre-read afL(0), bf0(0)
  STG_A(0, 0, 0); STG_A(0, 0, 2);
  STG_B(0, 0, 0); STG_B(0, 0, 1);
  STG_B(0, 0, 2); STG_B(0, 0, 3);
  STG_A(0, 0, 1); STG_A(0, 0, 3);
  VMCNT0; BAR;
  ldA(afL, A0, aRB, ak0, ak1);
  ldB(bfA, B0, bRB, ak0, ak1);

#define TILE(AB, BB, ABn, BBn, NBO, t, BF0, BF0N)                  \
  {                                                                \
    const int tn = ((t) + 1 < nt) ? (t) + 1 : nt - 1;              \
    /* W0: MFMA Q00; prefetch bf1(t) */                            \
    LGKM0; SCHED0;                                                 \
    ldB(bfB, BB, bRB + 8192, ak0, ak1);                            \
    mfmaQ<0, 0>(acc, afL, BF0);                                    \
    STG_A(NBO, tn, 0); STG_A(NBO, tn, 2);                          \
    VMCNT2; BAR;                                                   \
    /* W1: MFMA Q01; prefetch afH(t) */                            \
    LGKM0; SCHED0;                                                 \
    ldA(afH, AB, aRB + 4096, ak0, ak1);                            \
    mfmaQ<0, 1>(acc, afL, bfB);                                    \
    STG_B(NBO, tn, 0); STG_B(NBO, tn, 1);                          \
    VMCNT2; BAR;                                                   \
    /* W2: MFMA Q11; prefetch afL(t+1) from next buffer */         \
    LGKM0; SCHED0;                                                 \
    ldA(afL, ABn, aRB, ak0, ak1);                                  \
    mfmaQ<1, 1>(acc, afH, bfB);                                    \
    STG_B(NBO, tn, 2); STG_B(NBO, tn, 3);                          \
    VMCNT2; BAR;                                                   \
    /* W3: MFMA Q10; prefetch bf0(t+1) from next buffer */         \
    LGKM0; SCHED0;                                                 \
    ldB(BF0N, BBn, bRB, ak0, ak1);                                 \
    mfmaQ<1, 0>(acc, afH, BF0);                                    \
    STG_A(NBO, tn, 1); STG_A(NBO, tn, 3);                          \
    VMCNT2; BAR;                                                   \
  }

  for (int t = 0; t < nt; t += 2) {
    TILE(A0, B0, A1, B1, 65536, t,     bfA, bfC);
    TILE(A1, B1, A0, B0, 0,     t + 1, bfC, bfA);
  }
  VMCNT0;  // drain LDS-DMA (tail restage never consumed)

  // epilogue: D row=(lane>>4)*4+reg, col=lane&15
  const int rb = bm + wr * 128 + ((lane >> 4) << 2);
  const int cb = bn + wc * 64 + (lane & 15);
#pragma unroll
  for (int mi = 0; mi < 8; ++mi)
#pragma unroll
    for (int nj = 0; nj < 4; ++nj) {
      f32x4 v = acc[mi][nj];
#pragma unroll
      for (int rg = 0; rg < 4; ++rg)
        Cg[(size_t)(rb + mi * 16 + rg) * N + cb + nj * 16] = (CT)v[rg];
    }
#undef TILE
#undef STG_A
#undef STG_B
}

// ---------------- launcher ----------------
extern "C" void kernel_launch(void* const* d_in, const int* in_sizes, int n_in,
                              void* d_out, int out_size, void* d_ws, size_t ws_size,
                              hipStream_t stream) {
  const float* X  = (const float*)d_in[0];  // [2,4096,2048]
  const float* Wi = (const float*)d_in[1];  // [6144,2048]
  const float* Wc = (const float*)d_in[2];  // [2048,1,3]
  const float* Wo = (const float*)d_in[3];  // [2048,2048]
  float* out = (float*)d_out;               // [2,4096,2048] fp32

  char* ws = (char*)d_ws;
  _Float16* Xh   = (_Float16*)(ws);                    // 33,554,432 B
  _Float16* Wih  = (_Float16*)(ws + 33554432);         // 25,165,824 B
  _Float16* Woh  = (_Float16*)(ws + 58720256);         //  8,388,608 B
  _Float16* BCxh = (_Float16*)(ws + 67108864);         // 100,663,296 B
  _Float16* Yh   = (_Float16*)(ws + 167772160);        // 33,554,432 B
  (void)ws_size; (void)in_sizes; (void)n_in; (void)out_size;

  cvt_f32_f16<<<dim3(16777216 / 2048), 256, 0, stream>>>(X,  Xh,  16777216);
  cvt_f32_f16<<<dim3(12582912 / 2048), 256, 0, stream>>>(Wi, Wih, 12582912);
  cvt_f32_f16<<<dim3( 4194304 / 2048), 256, 0, stream>>>(Wo, Woh,  4194304);

  // in_proj: [8192,2048] x [6144,2048]^T -> BCx fp16   (32 x 24 = 768 blocks)
  gemm8p<_Float16><<<dim3(768), 512, 0, stream>>>(Xh, Wih, BCxh, 6144, 2048, 24);

  conv_gate<<<dim3(1024), 256, 0, stream>>>(BCxh, Wc, Yh);

  // out_proj: [8192,2048] x [2048,2048]^T -> out fp32  (32 x 8 = 256 blocks; N=2048)
  gemm8p<float><<<dim3(256), 512, 0, stream>>>(Yh, Woh, out, 2048, 2048, 8);
}

// Round 9
// 297.682 us; speedup vs baseline: 1.0289x; 1.0289x over previous
//
#include <hip/hip_runtime.h>
#include <hip/hip_fp16.h>

// LFM2 short-conv block. Round 9: prefetch-after-MFMA windows with ZERO register
// growth (same-variable fragment reload). r8's register-cost spill (WRITE_SIZE
// 98->104 MB) is avoided; the MFMA/LDS overlap is kept.

typedef _Float16 f16x8 __attribute__((ext_vector_type(8)));
typedef float    f32x4 __attribute__((ext_vector_type(4)));

#define GLD_LDS16(gsrc, sdst) \
  __builtin_amdgcn_global_load_lds((const __attribute__((address_space(1))) void*)(gsrc), \
                                   (__attribute__((address_space(3))) void*)(sdst), 16, 0, 0)

#define VMCNT4 asm volatile("s_waitcnt vmcnt(4)" ::: "memory")
#define VMCNT2 asm volatile("s_waitcnt vmcnt(2)" ::: "memory")
#define VMCNT0 asm volatile("s_waitcnt vmcnt(0)" ::: "memory")
#define LGKM0  asm volatile("s_waitcnt lgkmcnt(0)" ::: "memory")
#define BAR    __builtin_amdgcn_s_barrier()
#define SCHED0 __builtin_amdgcn_sched_barrier(0)

// ---------------- fused fp32 -> fp16 convert of X, W_in, W_out ----------------
__global__ __launch_bounds__(256) void cvt_all(const float* __restrict__ X,
                                               const float* __restrict__ Wi,
                                               const float* __restrict__ Wo,
                                               _Float16* __restrict__ Xh,
                                               _Float16* __restrict__ Wih,
                                               _Float16* __restrict__ Woh) {
  int base = (blockIdx.x * 256 + threadIdx.x) * 8;   // total 33,554,432 elems
  const float* src;
  _Float16* dst;
  int off;
  if (base < 16777216)      { src = X;  dst = Xh;  off = base; }
  else if (base < 29360128) { src = Wi; dst = Wih; off = base - 16777216; }
  else                      { src = Wo; dst = Woh; off = base - 29360128; }
  const float4* p = reinterpret_cast<const float4*>(src + off);
  float4 a = p[0], b = p[1];
  f16x8 o;
  o[0] = (_Float16)a.x; o[1] = (_Float16)a.y; o[2] = (_Float16)a.z; o[3] = (_Float16)a.w;
  o[4] = (_Float16)b.x; o[5] = (_Float16)b.y; o[6] = (_Float16)b.z; o[7] = (_Float16)b.w;
  *reinterpret_cast<f16x8*>(dst + off) = o;
}

// ---------------- conv + gating: y = Cg * causal_conv3(Bg * x) ----------------
__global__ __launch_bounds__(256) void conv_gate(const _Float16* __restrict__ BCx,
                                                 const float* __restrict__ Wc,   // [2048,1,3]
                                                 _Float16* __restrict__ Y) {
  const int h0 = threadIdx.x * 8;
  const int r0 = blockIdx.x * 8;
  const int s0 = r0 & 4095;

  float w0[8], w1[8], w2[8];
#pragma unroll
  for (int j = 0; j < 8; ++j) {
    w0[j] = Wc[(h0 + j) * 3 + 0];
    w1[j] = Wc[(h0 + j) * 3 + 1];
    w2[j] = Wc[(h0 + j) * 3 + 2];
  }

  float bxm2[8] = {}, bxm1[8] = {};
  if (s0 != 0) {
    const _Float16* pm2 = BCx + (size_t)(r0 - 2) * 6144 + h0;
    const _Float16* pm1 = BCx + (size_t)(r0 - 1) * 6144 + h0;
    f16x8 bg2 = *reinterpret_cast<const f16x8*>(pm2);
    f16x8 xx2 = *reinterpret_cast<const f16x8*>(pm2 + 4096);
    f16x8 bg1 = *reinterpret_cast<const f16x8*>(pm1);
    f16x8 xx1 = *reinterpret_cast<const f16x8*>(pm1 + 4096);
#pragma unroll
    for (int j = 0; j < 8; ++j) {
      bxm2[j] = (float)bg2[j] * (float)xx2[j];
      bxm1[j] = (float)bg1[j] * (float)xx1[j];
    }
  }

  for (int i = 0; i < 8; ++i) {
    const _Float16* pr = BCx + (size_t)(r0 + i) * 6144 + h0;
    f16x8 bg = *reinterpret_cast<const f16x8*>(pr);
    f16x8 cg = *reinterpret_cast<const f16x8*>(pr + 2048);
    f16x8 xx = *reinterpret_cast<const f16x8*>(pr + 4096);
    f16x8 o;
#pragma unroll
    for (int j = 0; j < 8; ++j) {
      float bx   = (float)bg[j] * (float)xx[j];
      float conv = w0[j] * bxm2[j] + w1[j] * bxm1[j] + w2[j] * bx;
      o[j] = (_Float16)((float)cg[j] * conv);
      bxm2[j] = bxm1[j];
      bxm1[j] = bx;
    }
    *reinterpret_cast<f16x8*>(Y + (size_t)(r0 + i) * 2048 + h0) = o;
  }
}

// ---------------- fragment load helpers ----------------
__device__ __forceinline__ void ldA(f16x8 (&af)[4][2], const _Float16* p, int base, int ak0, int ak1) {
#pragma unroll
  for (int i = 0; i < 4; ++i) {
    af[i][0] = *(const f16x8*)(p + base + i * 1024 + ak0);
    af[i][1] = *(const f16x8*)(p + base + i * 1024 + ak1);
  }
}
__device__ __forceinline__ void ldB(f16x8 (&bf)[2][2], const _Float16* p, int base, int ak0, int ak1) {
#pragma unroll
  for (int j = 0; j < 2; ++j) {
    bf[j][0] = *(const f16x8*)(p + base + j * 1024 + ak0);
    bf[j][1] = *(const f16x8*)(p + base + j * 1024 + ak1);
  }
}
template <int QM, int QN>
__device__ __forceinline__ void mfmaQ(f32x4 (&acc)[8][4], const f16x8 (&af)[4][2], const f16x8 (&bf)[2][2]) {
  __builtin_amdgcn_s_setprio(1);
#pragma unroll
  for (int i = 0; i < 4; ++i)
#pragma unroll
    for (int j = 0; j < 2; ++j)
#pragma unroll
      for (int ks = 0; ks < 2; ++ks)
        acc[QM * 4 + i][QN * 2 + j] =
            __builtin_amdgcn_mfma_f32_16x16x32_f16(af[i][ks], bf[j][ks], acc[QM * 4 + i][QN * 2 + j], 0, 0, 0);
  __builtin_amdgcn_s_setprio(0);
}

// 256x256 NT GEMM, BK=64, 8 waves (2x4), 16x16x32 MFMA, 128KB static LDS.
// A LDS [256][64] fp16, phys 16B-chunk ^= (row&7) [T2]; gld_lds linear dest +
// inverse-swizzled per-lane SOURCE (rule 21).
// Window: {LGKM0; SCHED0; MFMA(operands loaded LAST window); loads(NEXT window,
// same-variable reload = zero reg growth); stage; vmcnt; BAR}.
// MFMA: W0:Q00(afL,bf0) W1:Q01(afL,bf1) W2:Q11(afH,bf1) W3:Q10(afH,bf0).
// Loads: W0: bf<-bf1(t); W1: af<-afH(t); W2: bf<-bf0(t); W3: af<-afL(t+1), bf<-bf0(t+1).
// Stages (buf t+1): W0: a'{0,2},b'{0,1} (4 DMA); W1: b'{2,3}; W2: a'{1,3}; W3: none.
// Waits: W0: vmcnt(4) [retires a13(t-1) -> afH readable W1]; W2: vmcnt(4)
// [retires a02,b01(t) -> readable W3]; W3: vmcnt(2) [retires b23(t) -> bf1
// readable W0(t+1)]. FIFO-audited; overwrites >=2 barriers after last reader.
// ARGS: N = C column stride, K = reduction dim, nbn = N/256.
template <typename CT>
__global__ __launch_bounds__(512, 2) void gemm8p(const _Float16* __restrict__ Ag,
                                                 const _Float16* __restrict__ Bg,
                                                 CT* __restrict__ Cg,
                                                 int N, int K, int nbn) {
  __shared__ __align__(16) char smem[131072];
  const int tid = threadIdx.x, lane = tid & 63, w = tid >> 6;
  const int wr = w >> 2, wc = w & 3;

  // T1: XCD-bijective block swizzle (grid % 8 == 0)
  const int nwg = (int)gridDim.x, q8 = nwg >> 3;
  const int swz = ((int)blockIdx.x & 7) * q8 + ((int)blockIdx.x >> 3);
  const int bm = (swz / nbn) << 8, bn = (swz % nbn) << 8;

  _Float16* const A0 = (_Float16*)(smem);
  _Float16* const B0 = (_Float16*)(smem + 32768);
  _Float16* const A1 = (_Float16*)(smem + 65536);
  _Float16* const B1 = (_Float16*)(smem + 98304);

  const int rr = tid >> 3;
  const int sCol = ((tid & 7) ^ (rr & 7)) * 8;                  // inverse-swizzled source chunk
  const _Float16* aSrc = Ag + (size_t)(bm + rr) * K + sCol;
  const _Float16* bSrc = Bg + (size_t)(bn + (rr >> 5) * 64 + (rr & 31)) * K + sCol;

  // read-side swizzle folds to per-lane constants (row&7 == lane&7 for all read rows)
  const int ak0 = ((lane >> 4) ^ (lane & 7)) * 8;
  const int ak1 = (((lane >> 4) + 4) ^ (lane & 7)) * 8;
  const int aRB = (wr * 128 + (lane & 15)) * 64;
  const int bRB = (wc * 32 + (lane & 15)) * 64;

  const int nt = K >> 6;

#define STG_A(NBO, kt, u) GLD_LDS16(aSrc + (size_t)(u) * 64 * K + (kt) * 64, \
                                    smem + (NBO) + (u) * 8192 + tid * 16)
#define STG_B(NBO, kt, u) GLD_LDS16(bSrc + (size_t)(((u) & 1) * 128 + ((u) >> 1) * 32) * K + (kt) * 64, \
                                    smem + (NBO) + 32768 + (u) * 8192 + tid * 16)

  f16x8 af[4][2], bf[2][2];
  f32x4 acc[8][4] = {};

  // prologue: stage tile 0 -> buffer 0 (order a02,b01,b23,a13), drain, pre-read
  // afL(0), bf0(0) for W0's MFMA.
  STG_A(0, 0, 0); STG_A(0, 0, 2);
  STG_B(0, 0, 0); STG_B(0, 0, 1);
  STG_B(0, 0, 2); STG_B(0, 0, 3);
  STG_A(0, 0, 1); STG_A(0, 0, 3);
  VMCNT0; BAR;
  ldA(af, A0, aRB, ak0, ak1);
  ldB(bf, B0, bRB, ak0, ak1);

#define TILE(AB, BB, ABn, BBn, NBO, t)                             \
  {                                                                \
    const int tn = ((t) + 1 < nt) ? (t) + 1 : nt - 1;              \
    /* W0: Q00(afL,bf0); load bf1(t); stage a02'+b01' */           \
    LGKM0; SCHED0;                                                 \
    mfmaQ<0, 0>(acc, af, bf);                                      \
    ldB(bf, BB, bRB + 8192, ak0, ak1);                             \
    STG_A(NBO, tn, 0); STG_A(NBO, tn, 2);                          \
    STG_B(NBO, tn, 0); STG_B(NBO, tn, 1);                          \
    VMCNT4; BAR;                                                   \
    /* W1: Q01(afL,bf1); load afH(t); stage b23' */                \
    LGKM0; SCHED0;                                                 \
    mfmaQ<0, 1>(acc, af, bf);                                      \
    ldA(af, AB, aRB + 4096, ak0, ak1);                             \
    STG_B(NBO, tn, 2); STG_B(NBO, tn, 3);                          \
    BAR;                                                           \
    /* W2: Q11(afH,bf1); load bf0(t) re-read; stage a13' */        \
    LGKM0; SCHED0;                                                 \
    mfmaQ<1, 1>(acc, af, bf);                                      \
    ldB(bf, BB, bRB, ak0, ak1);                                    \
    STG_A(NBO, tn, 1); STG_A(NBO, tn, 3);                          \
    VMCNT4; BAR;                                                   \
    /* W3: Q10(afH,bf0); load afL(t+1), bf0(t+1) from next buf */  \
    LGKM0; SCHED0;                                                 \
    mfmaQ<1, 0>(acc, af, bf);                                      \
    ldA(af, ABn, aRB, ak0, ak1);                                   \
    ldB(bf, BBn, bRB, ak0, ak1);                                   \
    VMCNT2; BAR;                                                   \
  }

  for (int t = 0; t < nt; t += 2) {
    TILE(A0, B0, A1, B1, 65536, t);
    TILE(A1, B1, A0, B0, 0, t + 1);
  }
  VMCNT0;  // drain remaining LDS-DMA (tail restage never consumed)

  // epilogue: D row=(lane>>4)*4+reg, col=lane&15
  const int rb = bm + wr * 128 + ((lane >> 4) << 2);
  const int cb = bn + wc * 64 + (lane & 15);
#pragma unroll
  for (int mi = 0; mi < 8; ++mi)
#pragma unroll
    for (int nj = 0; nj < 4; ++nj) {
      f32x4 v = acc[mi][nj];
#pragma unroll
      for (int rg = 0; rg < 4; ++rg)
        Cg[(size_t)(rb + mi * 16 + rg) * N + cb + nj * 16] = (CT)v[rg];
    }
#undef TILE
#undef STG_A
#undef STG_B
}

// ---------------- launcher ----------------
extern "C" void kernel_launch(void* const* d_in, const int* in_sizes, int n_in,
                              void* d_out, int out_size, void* d_ws, size_t ws_size,
                              hipStream_t stream) {
  const float* X  = (const float*)d_in[0];  // [2,4096,2048]
  const float* Wi = (const float*)d_in[1];  // [6144,2048]
  const float* Wc = (const float*)d_in[2];  // [2048,1,3]
  const float* Wo = (const float*)d_in[3];  // [2048,2048]
  float* out = (float*)d_out;               // [2,4096,2048] fp32

  char* ws = (char*)d_ws;
  _Float16* Xh   = (_Float16*)(ws);                    // 33,554,432 B
  _Float16* Wih  = (_Float16*)(ws + 33554432);         // 25,165,824 B
  _Float16* Woh  = (_Float16*)(ws + 58720256);         //  8,388,608 B
  _Float16* BCxh = (_Float16*)(ws + 67108864);         // 100,663,296 B
  _Float16* Yh   = (_Float16*)(ws + 167772160);        // 33,554,432 B
  (void)ws_size; (void)in_sizes; (void)n_in; (void)out_size;

  // one fused convert kernel: 33,554,432 elems / 8 per thread / 256 = 16384 blocks
  cvt_all<<<dim3(16384), 256, 0, stream>>>(X, Wi, Wo, Xh, Wih, Woh);

  // in_proj: [8192,2048] x [6144,2048]^T -> BCx fp16   (32 x 24 = 768 blocks)
  gemm8p<_Float16><<<dim3(768), 512, 0, stream>>>(Xh, Wih, BCxh, 6144, 2048, 24);

  conv_gate<<<dim3(1024), 256, 0, stream>>>(BCxh, Wc, Yh);

  // out_proj: [8192,2048] x [2048,2048]^T -> out fp32  (32 x 8 = 256 blocks; N=2048)
  gemm8p<float><<<dim3(256), 512, 0, stream>>>(Yh, Woh, out, 2048, 2048, 8);
}